// Round 1
// baseline (853.785 us; speedup 1.0000x reference)
//
#include <hip/hip_runtime.h>
#include <cstdint>

#define TOKENS 16384
#define IN_F   4096
#define OUT_F  4096

typedef int v4i __attribute__((ext_vector_type(4)));

// --- async global->LDS, 16B per lane (dest = wave-uniform base + lane*16) ---
__device__ __forceinline__ void async_lds16(const void* g, const void* l) {
    __builtin_amdgcn_global_load_lds(
        (const __attribute__((address_space(1))) void*)(uintptr_t)g,
        (__attribute__((address_space(3))) void*)(uint32_t)(uintptr_t)l,
        16, 0, 0);
}

// ---------------------------------------------------------------------------
// Kernel 1: per-token dynamic int8 quant of x. One block (256 thr) per row.
// Writes packed int8 q_x [TOKENS][IN_F] and act_scale [TOKENS].
// ---------------------------------------------------------------------------
__global__ __launch_bounds__(256) void act_quant_kernel(
        const float* __restrict__ x,
        signed char* __restrict__ qx,
        float* __restrict__ act_scale) {
    const int row = blockIdx.x;
    const int tid = threadIdx.x;
    const float4* xr = (const float4*)(x + (size_t)row * IN_F);

    float4 v[4];
    float m = 0.f;
#pragma unroll
    for (int i = 0; i < 4; ++i) {
        v[i] = xr[i * 256 + tid];
        m = fmaxf(m, fmaxf(fmaxf(fabsf(v[i].x), fabsf(v[i].y)),
                           fmaxf(fabsf(v[i].z), fabsf(v[i].w))));
    }
    // wave (64-lane) butterfly reduce, then cross-wave via LDS
#pragma unroll
    for (int off = 32; off > 0; off >>= 1)
        m = fmaxf(m, __shfl_xor(m, off, 64));
    __shared__ float wmax[4];
    if ((tid & 63) == 0) wmax[tid >> 6] = m;
    __syncthreads();
    m = fmaxf(fmaxf(wmax[0], wmax[1]), fmaxf(wmax[2], wmax[3]));

    const float inv = (m == 0.f) ? 0.f : 127.0f / m;
    if (tid == 0) act_scale[row] = (m == 0.f) ? 1.0f : m / 127.0f;

    int* qr = (int*)(qx + (size_t)row * IN_F);
#pragma unroll
    for (int i = 0; i < 4; ++i) {
        // round-half-even (matches jnp.round), clamp to [-128,127]
        int q0 = (int)fminf(fmaxf(rintf(v[i].x * inv), -128.f), 127.f);
        int q1 = (int)fminf(fmaxf(rintf(v[i].y * inv), -128.f), 127.f);
        int q2 = (int)fminf(fmaxf(rintf(v[i].z * inv), -128.f), 127.f);
        int q3 = (int)fminf(fmaxf(rintf(v[i].w * inv), -128.f), 127.f);
        qr[i * 256 + tid] = (q0 & 255) | ((q1 & 255) << 8) |
                            ((q2 & 255) << 16) | ((q3 & 255) << 24);
    }
}

// ---------------------------------------------------------------------------
// Kernel 2: unpack int4 nibbles (one byte per int32) -> int8 [OUT_F][IN_F].
// high nibble -> even k, low nibble -> odd k.
// ---------------------------------------------------------------------------
__global__ __launch_bounds__(256) void unpack_w_kernel(
        const int* __restrict__ qw,
        signed char* __restrict__ w8) {
    const size_t idx = ((size_t)blockIdx.x * 256 + threadIdx.x) * 4;
    const int4 q = *(const int4*)(qw + idx);
    const int b0 = ((((q.x >> 4) & 15) - 8) & 255);
    const int b1 = (((q.x & 15) - 8) & 255);
    const int b2 = ((((q.y >> 4) & 15) - 8) & 255);
    const int b3 = (((q.y & 15) - 8) & 255);
    const int b4 = ((((q.z >> 4) & 15) - 8) & 255);
    const int b5 = (((q.z & 15) - 8) & 255);
    const int b6 = ((((q.w >> 4) & 15) - 8) & 255);
    const int b7 = (((q.w & 15) - 8) & 255);
    int2 d;
    d.x = b0 | (b1 << 8) | (b2 << 16) | (b3 << 24);
    d.y = b4 | (b5 << 8) | (b6 << 16) | (b7 << 24);
    *(int2*)(w8 + idx * 2) = d;
}

// ---------------------------------------------------------------------------
// Kernel 3: int8 GEMM, C[m][n] = sum_k qx[m][k]*w8[n][k], scaled epilogue.
// 128x128 tile, BK=64, 256 threads = 4 waves (2x2), each wave 64x64 via
// 4x4 grid of v_mfma_i32_16x16x64_i8. global_load_lds width=16 staging.
// ---------------------------------------------------------------------------
__global__ __launch_bounds__(256) void gemm_i8_kernel(
        const signed char* __restrict__ qx,
        const signed char* __restrict__ w8,
        const float* __restrict__ act_scale,
        const float* __restrict__ wscale,
        const float* __restrict__ bias,
        float* __restrict__ out) {
    __shared__ __align__(16) signed char sA[128 * 64];
    __shared__ __align__(16) signed char sB[128 * 64];

    const int nt = blockIdx.x & 31;       // OUT_F/128 = 32 n-tiles
    const int mt = blockIdx.x >> 5;       // TOKENS/128 = 128 m-tiles
    const int m0 = mt * 128, n0 = nt * 128;
    const int tid  = threadIdx.x;
    const int lane = tid & 63;
    const int wave = tid >> 6;
    const int wm = (wave >> 1) * 64;      // wave's row offset in tile
    const int wn = (wave & 1) * 64;       // wave's col offset in tile

    // staging: each wave fills 32 rows of each tile (2 issues x 16 rows).
    // lane's chunk: row = base + lane/4, col = (lane%4)*16  (== lane*16 flat)
    const int srow = wave * 32 + (lane >> 2);
    const int scol = (lane & 3) * 16;
    const signed char* gA = qx + (size_t)(m0 + srow) * IN_F + scol;
    const signed char* gB = w8 + (size_t)(n0 + srow) * IN_F + scol;
    signed char* lA = sA + wave * 2048;
    signed char* lB = sB + wave * 2048;

    v4i acc[4][4];
#pragma unroll
    for (int i = 0; i < 4; ++i)
#pragma unroll
        for (int j = 0; j < 4; ++j) acc[i][j] = (v4i){0, 0, 0, 0};

    // fragment read: lane holds [row = frow][k = fcol..fcol+15]
    const int frow = lane & 15;
    const int fcol = (lane >> 4) * 16;

    for (int k0 = 0; k0 < IN_F; k0 += 64) {
        __syncthreads();  // protect LDS from overwrite while prior reads run
        async_lds16(gA + k0,              lA);
        async_lds16(gA + k0 + 16 * IN_F,  lA + 1024);
        async_lds16(gB + k0,              lB);
        async_lds16(gB + k0 + 16 * IN_F,  lB + 1024);
        __syncthreads();  // barrier drains vmcnt -> LDS data ready

        v4i af[4], bf[4];
#pragma unroll
        for (int i = 0; i < 4; ++i)
            af[i] = *(const v4i*)(sA + (wm + i * 16 + frow) * 64 + fcol);
#pragma unroll
        for (int j = 0; j < 4; ++j)
            bf[j] = *(const v4i*)(sB + (wn + j * 16 + frow) * 64 + fcol);

#pragma unroll
        for (int i = 0; i < 4; ++i)
#pragma unroll
            for (int j = 0; j < 4; ++j)
                acc[i][j] = __builtin_amdgcn_mfma_i32_16x16x64_i8(
                    af[i], bf[j], acc[i][j], 0, 0, 0);
    }

    // epilogue: out[m][n] = acc * act_scale[m]*wscale[n] + bias[n]
    // C/D mapping (shape-determined): col = lane&15, row = (lane>>4)*4 + reg
    const int col_lane = lane & 15;
    const int row_q    = (lane >> 4) * 4;
    float4 as4[4];
#pragma unroll
    for (int i = 0; i < 4; ++i)
        as4[i] = *(const float4*)(act_scale + m0 + wm + i * 16 + row_q);

#pragma unroll
    for (int j = 0; j < 4; ++j) {
        const int n = n0 + wn + j * 16 + col_lane;
        const float wsn = wscale[n];
        const float bn  = bias[n];
#pragma unroll
        for (int i = 0; i < 4; ++i) {
            const int mb = m0 + wm + i * 16 + row_q;
            float* orow = out + (size_t)mb * OUT_F + n;
            const float* asp = (const float*)&as4[i];
#pragma unroll
            for (int r = 0; r < 4; ++r)
                orow[(size_t)r * OUT_F] = (float)acc[i][j][r] * (asp[r] * wsn) + bn;
        }
    }
}

// ---------------------------------------------------------------------------
extern "C" void kernel_launch(void* const* d_in, const int* in_sizes, int n_in,
                              void* d_out, int out_size, void* d_ws, size_t ws_size,
                              hipStream_t stream) {
    const float* x    = (const float*)d_in[0];
    const int*   qw   = (const int*)d_in[1];
    const float* wsc  = (const float*)d_in[2];
    const float* bias = (const float*)d_in[3];
    float* out = (float*)d_out;

    // workspace layout: [act_scale 64KB][qx 64MB][w8 16MB]  (~80.1 MB total)
    char* ws = (char*)d_ws;
    float*       act_scale = (float*)ws;
    signed char* qx        = (signed char*)(ws + 65536);
    signed char* w8        = (signed char*)(ws + 65536 + (size_t)TOKENS * IN_F);

    act_quant_kernel<<<TOKENS, 256, 0, stream>>>(x, qx, act_scale);
    unpack_w_kernel<<<(OUT_F * (IN_F / 2) / 4) / 256, 256, 0, stream>>>(qw, w8);
    gemm_i8_kernel<<<(TOKENS / 128) * (OUT_F / 128), 256, 0, stream>>>(
        qx, w8, act_scale, wsc, bias, out);
}

// Round 2
// 849.445 us; speedup vs baseline: 1.0051x; 1.0051x over previous
//
#include <hip/hip_runtime.h>
#include <cstdint>

#define TOKENS 16384
#define IN_F   4096
#define OUT_F  4096

typedef int v4i __attribute__((ext_vector_type(4)));

// --- async global->LDS, 16B per lane (dest = wave-uniform base + lane*16) ---
__device__ __forceinline__ void async_lds16(const void* g, const void* l) {
    __builtin_amdgcn_global_load_lds(
        (const __attribute__((address_space(1))) void*)(uintptr_t)g,
        (__attribute__((address_space(3))) void*)(uint32_t)(uintptr_t)l,
        16, 0, 0);
}

// ---------------------------------------------------------------------------
// Kernel 1: per-token dynamic int8 quant of x. One block (256 thr) per row.
// ---------------------------------------------------------------------------
__global__ __launch_bounds__(256) void act_quant_kernel(
        const float* __restrict__ x,
        signed char* __restrict__ qx,
        float* __restrict__ act_scale) {
    const int row = blockIdx.x;
    const int tid = threadIdx.x;
    const float4* xr = (const float4*)(x + (size_t)row * IN_F);

    float4 v[4];
    float m = 0.f;
#pragma unroll
    for (int i = 0; i < 4; ++i) {
        v[i] = xr[i * 256 + tid];
        m = fmaxf(m, fmaxf(fmaxf(fabsf(v[i].x), fabsf(v[i].y)),
                           fmaxf(fabsf(v[i].z), fabsf(v[i].w))));
    }
#pragma unroll
    for (int off = 32; off > 0; off >>= 1)
        m = fmaxf(m, __shfl_xor(m, off, 64));
    __shared__ float wmax[4];
    if ((tid & 63) == 0) wmax[tid >> 6] = m;
    __syncthreads();
    m = fmaxf(fmaxf(wmax[0], wmax[1]), fmaxf(wmax[2], wmax[3]));

    const float inv = (m == 0.f) ? 0.f : 127.0f / m;
    if (tid == 0) act_scale[row] = (m == 0.f) ? 1.0f : m / 127.0f;

    int* qr = (int*)(qx + (size_t)row * IN_F);
#pragma unroll
    for (int i = 0; i < 4; ++i) {
        int q0 = (int)fminf(fmaxf(rintf(v[i].x * inv), -128.f), 127.f);
        int q1 = (int)fminf(fmaxf(rintf(v[i].y * inv), -128.f), 127.f);
        int q2 = (int)fminf(fmaxf(rintf(v[i].z * inv), -128.f), 127.f);
        int q3 = (int)fminf(fmaxf(rintf(v[i].w * inv), -128.f), 127.f);
        qr[i * 256 + tid] = (q0 & 255) | ((q1 & 255) << 8) |
                            ((q2 & 255) << 16) | ((q3 & 255) << 24);
    }
}

// ---------------------------------------------------------------------------
// Kernel 2: unpack int4 nibbles -> int8 [OUT_F][IN_F].
// ---------------------------------------------------------------------------
__global__ __launch_bounds__(256) void unpack_w_kernel(
        const int* __restrict__ qw,
        signed char* __restrict__ w8) {
    const size_t idx = ((size_t)blockIdx.x * 256 + threadIdx.x) * 4;
    const int4 q = *(const int4*)(qw + idx);
    const int b0 = ((((q.x >> 4) & 15) - 8) & 255);
    const int b1 = (((q.x & 15) - 8) & 255);
    const int b2 = ((((q.y >> 4) & 15) - 8) & 255);
    const int b3 = (((q.y & 15) - 8) & 255);
    const int b4 = ((((q.z >> 4) & 15) - 8) & 255);
    const int b5 = (((q.z & 15) - 8) & 255);
    const int b6 = ((((q.w >> 4) & 15) - 8) & 255);
    const int b7 = (((q.w & 15) - 8) & 255);
    int2 d;
    d.x = b0 | (b1 << 8) | (b2 << 16) | (b3 << 24);
    d.y = b4 | (b5 << 8) | (b6 << 16) | (b7 << 24);
    *(int2*)(w8 + idx * 2) = d;
}

// ---------------------------------------------------------------------------
// Kernel 3: int8 GEMM. BM=128, BN=256, BK=64. 256 thr = 4 waves (2x2),
// wave tile 64x128 = 4x8 grid of v_mfma_i32_16x16x64_i8.
//
// LDS layout is FRAGMENT-ORDER: tile row-group g (rows 16g..16g+15) is one
// 1 KiB block; slot l in [0,64) at g*1024 + l*16 holds (row=16g+(l&15),
// kchunk=l>>4). Consequences:
//   - global_load_lds: dest = group base + lane*16 (HW requirement), lane
//     fetches global (row = 16g + (lane&15), k = (lane>>4)*16) -> trivial.
//   - fragment ds_read_b128: af[i] = group base + lane*16 -> stride-1,
//     ZERO bank conflicts (was 8-way with row-major 64B-stride layout).
// ---------------------------------------------------------------------------
__global__ __launch_bounds__(256, 2) void gemm_i8_kernel(
        const signed char* __restrict__ qx,
        const signed char* __restrict__ w8,
        const float* __restrict__ act_scale,
        const float* __restrict__ wscale,
        const float* __restrict__ bias,
        float* __restrict__ out) {
    __shared__ __align__(16) signed char sA[128 * 64];   //  8 groups x 1 KiB
    __shared__ __align__(16) signed char sB[256 * 64];   // 16 groups x 1 KiB

    const int nt = blockIdx.x & 15;       // OUT_F/256 = 16 n-tiles
    const int mt = blockIdx.x >> 4;       // TOKENS/128 = 128 m-tiles
    const int m0 = mt * 128, n0 = nt * 256;
    const int tid  = threadIdx.x;
    const int lane = tid & 63;
    const int wave = tid >> 6;
    const int wm = (wave >> 1) * 64;      // wave row offset (0 or 64)
    const int wn = (wave & 1) * 128;      // wave col offset (0 or 128)

    // staging: wave w fills A-groups {2w,2w+1}, B-groups {4w..4w+3}.
    // lane's global element for group g: row = 16g + (lane&15), k = (lane>>4)*16
    const int lrow = lane & 15;
    const int lcol = (lane >> 4) * 16;
    const signed char* gA0 = qx + (size_t)(m0 + 16 * (2 * wave)     + lrow) * IN_F + lcol;
    const signed char* gA1 = qx + (size_t)(m0 + 16 * (2 * wave + 1) + lrow) * IN_F + lcol;
    const signed char* gB0 = w8 + (size_t)(n0 + 16 * (4 * wave)     + lrow) * IN_F + lcol;
    const signed char* gB1 = w8 + (size_t)(n0 + 16 * (4 * wave + 1) + lrow) * IN_F + lcol;
    const signed char* gB2 = w8 + (size_t)(n0 + 16 * (4 * wave + 2) + lrow) * IN_F + lcol;
    const signed char* gB3 = w8 + (size_t)(n0 + 16 * (4 * wave + 3) + lrow) * IN_F + lcol;
    signed char* lA0 = sA + (2 * wave) * 1024;
    signed char* lA1 = lA0 + 1024;
    signed char* lB0 = sB + (4 * wave) * 1024;
    signed char* lB1 = lB0 + 1024;
    signed char* lB2 = lB0 + 2048;
    signed char* lB3 = lB0 + 3072;

    v4i acc[4][8];
#pragma unroll
    for (int i = 0; i < 4; ++i)
#pragma unroll
        for (int j = 0; j < 8; ++j) acc[i][j] = (v4i){0, 0, 0, 0};

    // fragment read bases (fragment-order layout: group base + lane*16)
    const signed char* fA = sA + (wm >> 4) * 1024 + lane * 16;
    const signed char* fB = sB + (wn >> 4) * 1024 + lane * 16;

    for (int k0 = 0; k0 < IN_F; k0 += 64) {
        __syncthreads();  // prior iter's LDS reads done before overwrite
        async_lds16(gA0 + k0, lA0);
        async_lds16(gA1 + k0, lA1);
        async_lds16(gB0 + k0, lB0);
        async_lds16(gB1 + k0, lB1);
        async_lds16(gB2 + k0, lB2);
        async_lds16(gB3 + k0, lB3);
        __syncthreads();  // barrier drains vmcnt -> staged data visible

        v4i af[4], bf[8];
#pragma unroll
        for (int i = 0; i < 4; ++i)
            af[i] = *(const v4i*)(fA + i * 1024);
#pragma unroll
        for (int j = 0; j < 8; ++j)
            bf[j] = *(const v4i*)(fB + j * 1024);

#pragma unroll
        for (int i = 0; i < 4; ++i)
#pragma unroll
            for (int j = 0; j < 8; ++j)
                acc[i][j] = __builtin_amdgcn_mfma_i32_16x16x64_i8(
                    af[i], bf[j], acc[i][j], 0, 0, 0);
    }

    // epilogue: out[m][n] = acc * act_scale[m]*wscale[n] + bias[n]
    // C/D mapping: col = lane&15, row = (lane>>4)*4 + reg
    const int col_lane = lane & 15;
    const int row_q    = (lane >> 4) * 4;
    float4 as4[4];
#pragma unroll
    for (int i = 0; i < 4; ++i)
        as4[i] = *(const float4*)(act_scale + m0 + wm + i * 16 + row_q);

#pragma unroll
    for (int j = 0; j < 8; ++j) {
        const int n = n0 + wn + j * 16 + col_lane;
        const float wsn = wscale[n];
        const float bn  = bias[n];
#pragma unroll
        for (int i = 0; i < 4; ++i) {
            const int mb = m0 + wm + i * 16 + row_q;
            float* orow = out + (size_t)mb * OUT_F + n;
            const float* asp = (const float*)&as4[i];
#pragma unroll
            for (int r = 0; r < 4; ++r)
                orow[(size_t)r * OUT_F] = (float)acc[i][j][r] * (asp[r] * wsn) + bn;
        }
    }
}

// ---------------------------------------------------------------------------
extern "C" void kernel_launch(void* const* d_in, const int* in_sizes, int n_in,
                              void* d_out, int out_size, void* d_ws, size_t ws_size,
                              hipStream_t stream) {
    const float* x    = (const float*)d_in[0];
    const int*   qw   = (const int*)d_in[1];
    const float* wsc  = (const float*)d_in[2];
    const float* bias = (const float*)d_in[3];
    float* out = (float*)d_out;

    char* ws = (char*)d_ws;
    float*       act_scale = (float*)ws;
    signed char* qx        = (signed char*)(ws + 65536);
    signed char* w8        = (signed char*)(ws + 65536 + (size_t)TOKENS * IN_F);

    act_quant_kernel<<<TOKENS, 256, 0, stream>>>(x, qx, act_scale);
    unpack_w_kernel<<<(OUT_F * (IN_F / 2) / 4) / 256, 256, 0, stream>>>(qw, w8);
    gemm_i8_kernel<<<(TOKENS / 128) * (OUT_F / 256), 256, 0, stream>>>(
        qx, w8, act_scale, wsc, bias, out);
}